// Round 6
// baseline (571.888 us; speedup 1.0000x reference)
//
#include <hip/hip_runtime.h>

#define D_MODEL 512
#define P_DIM 64
#define C_DIM 32
#define B_DIM 32
#define N_PATCH 2048   // C_DIM * P_DIM
#define SELECT_N 256

// Shared memory reused across the three phases (~17 KB):
struct SmemA { float wl[D_MODEL]; float red[16][16][4]; };                   // 6,144 B
struct SmemC { float tile[64][65]; int plist[64]; int ilist[64]; };          // 17,152 B
union __align__(16) Smem {
  SmemA a;
  unsigned long long key[N_PATCH];  // 16,384 B (sort)
  SmemC c;
};

// ---------------------------------------------------------------------------
// One fused kernel, 1024 blocks (one per (b,c)), no cooperative launch:
//   A) score own 128 KB tile (linear-copy access pattern)
//   B) last block of batch b (via cnt[b]) sorts the 2048 scores (bitonic,
//      8 elem/thread, register/wave-local to k=512) and releases flag[b]
//   C) every block re-reads its tile (L2/L3-hot) through LDS and writes its
//      channel's selected patches coalesced. Tile prefetch loads are issued
//      BEFORE the flag spin so sort latency hides under load latency.
// Cross-XCD visibility: writers __syncthreads (vmcnt drain) + __threadfence
// (wbl2 -> L3) before the device-scope atomic; readers acquire + fence, and
// first-touch reads miss local L2 -> L3 (fresh). Deadlock-free: LDS 17 KB +
// __launch_bounds__(256,4) => 4 blocks/CU => all 1024 blocks co-resident.
// Key = (monotone_bits<<32)|(2047-idx): exact jax.lax.top_k tie semantics.
// Bias unused: constant shift doesn't change selection; output is raw x.
// ---------------------------------------------------------------------------
__global__ __launch_bounds__(256, 4) void fused_kernel(
    const float* __restrict__ x, const float* __restrict__ w,
    float* __restrict__ scores, int* __restrict__ topk,
    unsigned* __restrict__ cnt, unsigned* __restrict__ flag,
    float* __restrict__ out) {
  __shared__ Smem sm;
  __shared__ int s_last;
  __shared__ int s_m;

  const int bc  = blockIdx.x;    // b*32 + c
  const int b   = bc >> 5;
  const int c   = bc & 31;
  const int tid = threadIdx.x;   // 256 threads

  // ------------------------- Phase A: scores ------------------------------
  for (int j = tid; j < D_MODEL; j += 256) sm.a.wl[j] = w[j];
  __syncthreads();

  const int pg    = tid & 15;    // float4 group over p
  const int slice = tid >> 4;    // 0..15
  {
    const float* base = x + (size_t)bc * (D_MODEL * P_DIM) + pg * 4;
    float4 acc = make_float4(0.f, 0.f, 0.f, 0.f);
#pragma unroll 16
    for (int i = 0; i < 32; ++i) {
      const int d = slice + 16 * i;          // wave-contiguous 1 KB segments
      const float wd = sm.a.wl[d];
      const float4 v = *(const float4*)(base + (size_t)d * P_DIM);
      acc.x += v.x * wd; acc.y += v.y * wd;
      acc.z += v.z * wd; acc.w += v.w * wd;
    }
    sm.a.red[slice][pg][0] = acc.x; sm.a.red[slice][pg][1] = acc.y;
    sm.a.red[slice][pg][2] = acc.z; sm.a.red[slice][pg][3] = acc.w;
    __syncthreads();
    if (tid < 16) {
      float s0 = 0.f, s1 = 0.f, s2 = 0.f, s3 = 0.f;
#pragma unroll
      for (int k = 0; k < 16; ++k) {
        s0 += sm.a.red[k][tid][0]; s1 += sm.a.red[k][tid][1];
        s2 += sm.a.red[k][tid][2]; s3 += sm.a.red[k][tid][3];
      }
      float* sc = scores + (size_t)bc * P_DIM + tid * 4;
      sc[0] = s0; sc[1] = s1; sc[2] = s2; sc[3] = s3;
    }
  }
  __syncthreads();   // barrier drains vmcnt(0): score stores are in L2
  __threadfence();   // wbl2: dirty score lines -> L3 (device visibility)
  if (tid == 0)
    s_last = (__hip_atomic_fetch_add(&cnt[b], 1u, __ATOMIC_ACQ_REL,
                                     __HIP_MEMORY_SCOPE_AGENT) == 31u);
  __syncthreads();

  // ---------------- Phase B: last block of batch sorts --------------------
  if (s_last) {
    unsigned long long e[8];
    {
      const float4 sA = *(const float4*)(scores + (size_t)b * N_PATCH + 8 * tid);
      const float4 sB = *(const float4*)(scores + (size_t)b * N_PATCH + 8 * tid + 4);
      const float sv[8] = {sA.x, sA.y, sA.z, sA.w, sB.x, sB.y, sB.z, sB.w};
#pragma unroll
      for (int r = 0; r < 8; ++r) {
        unsigned u = __float_as_uint(sv[r]);
        u ^= (u & 0x80000000u) ? 0xFFFFFFFFu : 0x80000000u;
        e[r] = ((unsigned long long)u << 32) |
               (unsigned)(N_PATCH - 1 - (8 * tid + r));
      }
    }
    auto cmpsel = [](unsigned long long& xx, unsigned long long& yy, bool desc) {
      const unsigned long long mx = xx > yy ? xx : yy;
      const unsigned long long mn = xx > yy ? yy : xx;
      xx = desc ? mx : mn; yy = desc ? mn : mx;
    };
    auto intra = [&](int j, int k) {
#pragma unroll
      for (int r = 0; r < 8; ++r)
        if ((r & j) == 0) {
          const bool desc = (((8 * tid + r) & k) == 0);
          cmpsel(e[r], e[r | j], desc);
        }
    };
    auto xl = [&](int j, int k) {
      const int lj = j >> 3;
      const bool lower = (tid & lj) == 0;
      const bool desc  = ((8 * tid & k) == 0);
      const bool keepmax = (lower == desc);
#pragma unroll
      for (int r = 0; r < 8; ++r) {
        const unsigned long long p = __shfl_xor(e[r], lj, 64);
        e[r] = keepmax ? (e[r] > p ? e[r] : p) : (e[r] < p ? e[r] : p);
      }
    };
    auto ldsp = [&](int j, int k) {
#pragma unroll
      for (int q = 0; q < 8; ++q) {
        const int i = tid + q * 256;
        if ((i & j) == 0) {
          const bool desc = ((i & k) == 0);
          const unsigned long long A = sm.key[i];
          const unsigned long long B = sm.key[i | j];
          if (desc ? (B > A) : (B < A)) { sm.key[i] = B; sm.key[i | j] = A; }
        }
      }
    };

#pragma unroll
    for (int kk = 1; kk <= 9; ++kk) {
      const int k = 1 << kk;
      for (int j = k >> 1; j >= 8; j >>= 1) xl(j, k);
      for (int j = (k > 8 ? 4 : (k >> 1)); j >= 1; j >>= 1) intra(j, k);
    }
#pragma unroll
    for (int r = 0; r < 8; ++r) sm.key[8 * tid + r] = e[r];
    __syncthreads();

    ldsp(512, 1024);
    __syncthreads();
#pragma unroll
    for (int r = 0; r < 8; ++r) e[r] = sm.key[8 * tid + r];
    for (int j = 256; j >= 8; j >>= 1) xl(j, 1024);
    for (int j = 4; j >= 1; j >>= 1) intra(j, 1024);
#pragma unroll
    for (int r = 0; r < 8; ++r) sm.key[8 * tid + r] = e[r];
    __syncthreads();

    ldsp(1024, 2048);
    __syncthreads();
    ldsp(512, 2048);
    __syncthreads();
#pragma unroll
    for (int r = 0; r < 8; ++r) e[r] = sm.key[8 * tid + r];
    for (int j = 256; j >= 8; j >>= 1) xl(j, 2048);
    for (int j = 4; j >= 1; j >>= 1) intra(j, 2048);

    if (tid < 32) {
#pragma unroll
      for (int r = 0; r < 8; ++r)
        topk[b * SELECT_N + 8 * tid + r] =
            (N_PATCH - 1) - (int)(e[r] & 0xFFFFFFFFu);
    }
    __syncthreads();   // drain topk stores (vmcnt 0 at barrier)
    __threadfence();   // flush to L3
    if (tid == 0)
      __hip_atomic_store(&flag[b], 1u, __ATOMIC_RELEASE,
                         __HIP_MEMORY_SCOPE_AGENT);
  }

  // ------------------------- Phase C: gather ------------------------------
  const int p4 = (tid & 15) * 4;   // float4 column within row
  const int r0 = tid >> 4;         // row within 16-row group
  const int jr = tid >> 6;         // wave id -> patch group
  const int dd = tid & 63;         // lane -> d offset
  const float* xb = x + (size_t)bc * (D_MODEL * P_DIM);

  // Issue chunk-0 tile loads NOW: they complete while we wait on flag[b].
  float4 pre[4];
#pragma unroll
  for (int q = 0; q < 4; ++q)
    pre[q] = *(const float4*)(xb + (size_t)(r0 + q * 16) * P_DIM + p4);

  if (tid == 0) {
    while (__hip_atomic_load(&flag[b], __ATOMIC_ACQUIRE,
                             __HIP_MEMORY_SCOPE_AGENT) == 0u)
      __builtin_amdgcn_s_sleep(8);
    s_m = 0;
  }
  __syncthreads();
  __threadfence();

  {
    const int n = topk[b * SELECT_N + tid];   // fresh via L3 (first touch)
    if ((n >> 6) == c) {
      const int slot = atomicAdd(&s_m, 1);
      sm.c.plist[slot] = n & 63;
      sm.c.ilist[slot] = tid;
    }
  }
  __syncthreads();
  const int m = s_m;
  if (m == 0) return;

  for (int d0 = 0; d0 < D_MODEL; d0 += 64) {
#pragma unroll
    for (int q = 0; q < 4; ++q) {
      const int drow = r0 + q * 16;
      sm.c.tile[drow][p4]     = pre[q].x;
      sm.c.tile[drow][p4 + 1] = pre[q].y;
      sm.c.tile[drow][p4 + 2] = pre[q].z;
      sm.c.tile[drow][p4 + 3] = pre[q].w;
    }
    __syncthreads();
    if (d0 + 64 < D_MODEL) {   // prefetch next chunk; overlaps out-writes
#pragma unroll
      for (int q = 0; q < 4; ++q)
        pre[q] = *(const float4*)(xb + (size_t)(d0 + 64 + r0 + q * 16) * P_DIM + p4);
    }
    for (int j = jr; j < m; j += 4)
      out[(size_t)(b * SELECT_N + sm.c.ilist[j]) * D_MODEL + d0 + dd] =
          sm.c.tile[dd][sm.c.plist[j]];
    __syncthreads();
  }
}

extern "C" void kernel_launch(void* const* d_in, const int* in_sizes, int n_in,
                              void* d_out, int out_size, void* d_ws, size_t ws_size,
                              hipStream_t stream) {
  const float* x = (const float*)d_in[0];
  const float* w = (const float*)d_in[1];
  // d_in[2] (bias) intentionally unused: constant shift doesn't change top-k.

  char* ws = (char*)d_ws;
  float*    scores = (float*)ws;                                   // 256 KB
  int*      topk   = (int*)(ws + B_DIM * N_PATCH * sizeof(float)); // 32 KB
  unsigned* cnt    = (unsigned*)(ws + B_DIM * N_PATCH * sizeof(float)
                                    + B_DIM * SELECT_N * sizeof(int));
  unsigned* flag   = cnt + B_DIM;
  float*    out    = (float*)d_out;

  // ws is poisoned 0xAA before every call: zero the 256 B of counters/flags.
  hipMemsetAsync(cnt, 0, 2 * B_DIM * sizeof(unsigned), stream);
  fused_kernel<<<B_DIM * C_DIM, 256, 0, stream>>>(x, w, scores, topk, cnt,
                                                  flag, out);
}

// Round 7
// 227.547 us; speedup vs baseline: 2.5133x; 2.5133x over previous
//
#include <hip/hip_runtime.h>

#define D_MODEL 512
#define P_DIM 64
#define C_DIM 32
#define B_DIM 32
#define N_PATCH 2048   // C_DIM * P_DIM
#define SELECT_N 256

typedef unsigned long long u64;

// ---------------------------------------------------------------------------
// K1: scores + per-chunk sort. One block per (b, chunk); chunk = 4 channels.
// Streams 512 KB (linear-copy pattern), produces 256 scores, bitonic-sorts
// the 256 keys (1 key/thread: stages k<=64 pure shfl, 3 LDS phases for
// j>=64), writes the sorted chunk as u64 keys.
// Key = (monotone_bits<<32) | (2047 - local_n): descending u64 order ==
// score desc, ties -> lower idx (exact jax.lax.top_k semantics; keys unique).
// Bias unused: constant shift doesn't change selection; output is raw x.
// ---------------------------------------------------------------------------
__global__ __launch_bounds__(256) void score_sort_kernel(
    const float* __restrict__ x, const float* __restrict__ w,
    u64* __restrict__ chunks) {
  __shared__ float wl[D_MODEL];
  __shared__ float4 red[16][16];
  __shared__ float cs[256];     // the chunk's 256 scores
  __shared__ u64 skey[256];     // sort scratch

  const int blk   = blockIdx.x;   // b*8 + chunk
  const int b     = blk >> 3;
  const int chunk = blk & 7;
  const int tid   = threadIdx.x;  // 256

  for (int j = tid; j < D_MODEL; j += 256) wl[j] = w[j];
  __syncthreads();

  const int pg    = tid & 15;     // float4 group over p
  const int slice = tid >> 4;     // 0..15

  for (int ch = 0; ch < 4; ++ch) {
    const int bc = b * C_DIM + chunk * 4 + ch;
    const float* base = x + (size_t)bc * (D_MODEL * P_DIM) + pg * 4;
    float4 acc = make_float4(0.f, 0.f, 0.f, 0.f);
#pragma unroll 8
    for (int i = 0; i < 32; ++i) {
      const int d = slice + 16 * i;          // wave-contiguous 1 KB segments
      const float wd = wl[d];
      const float4 v = *(const float4*)(base + (size_t)d * P_DIM);
      acc.x += v.x * wd; acc.y += v.y * wd;
      acc.z += v.z * wd; acc.w += v.w * wd;
    }
    red[slice][pg] = acc;
    __syncthreads();
    if (tid < 16) {
      float4 s = red[0][tid];
#pragma unroll
      for (int k = 1; k < 16; ++k) {
        const float4 t4 = red[k][tid];
        s.x += t4.x; s.y += t4.y; s.z += t4.z; s.w += t4.w;
      }
      cs[ch * 64 + tid * 4 + 0] = s.x;   // p = tid*4+q
      cs[ch * 64 + tid * 4 + 1] = s.y;
      cs[ch * 64 + tid * 4 + 2] = s.z;
      cs[ch * 64 + tid * 4 + 3] = s.w;
    }
    __syncthreads();   // cs visible; red reusable next channel
  }

  // Build key: local element t = ch*64 + p; local_n = chunk*256 + t.
  u64 e;
  {
    unsigned u = __float_as_uint(cs[tid]);
    u ^= (u & 0x80000000u) ? 0xFFFFFFFFu : 0x80000000u;
    e = ((u64)u << 32) | (unsigned)(N_PATCH - 1 - (chunk * 256 + tid));
  }

  auto ce1 = [&](int j, int k) {           // in-wave CE, pair (tid, tid^j)
    const u64 p = __shfl_xor(e, j, 64);
    const bool keepmax = (((tid & j) == 0) == ((tid & k) == 0));
    e = keepmax ? (e > p ? e : p) : (e < p ? e : p);
  };
  auto ldsce = [&](int j, int k) {         // LDS CE, one thread per pair
    if ((tid & j) == 0) {
      const bool desc = ((tid & k) == 0);
      const u64 A = skey[tid], B = skey[tid | j];
      if (desc ? (B > A) : (B < A)) { skey[tid] = B; skey[tid | j] = A; }
    }
  };

#pragma unroll
  for (int kk = 1; kk <= 6; ++kk) {        // stages k = 2..64: pure shfl
    const int k = 1 << kk;
    for (int j = k >> 1; j >= 1; j >>= 1) ce1(j, k);
  }
  // stage k = 128
  skey[tid] = e; __syncthreads();
  ldsce(64, 128); __syncthreads();
  e = skey[tid];
  for (int j = 32; j >= 1; j >>= 1) ce1(j, 128);
  // stage k = 256 (final, all-descending)
  skey[tid] = e; __syncthreads();
  ldsce(128, 256); __syncthreads();
  ldsce(64, 256); __syncthreads();
  e = skey[tid];
  for (int j = 32; j >= 1; j >>= 1) ce1(j, 256);

  chunks[(size_t)b * N_PATCH + chunk * 256 + tid] = e;  // sorted desc
}

// ---------------------------------------------------------------------------
// K2: merge-prune + gather. One block per (b,c). Loads batch b's 8 sorted
// chunks (16 KB, L2/L3-hot), and REDUNDANTLY (per block; avoids any
// cross-block sync — R4/R6 showed device-scope sync costs 200+ us here)
// reduces them to the sorted top-256 via bitonic merge-prune:
//   top-L of two desc L-lists = elementwise max(A[i], B[L-1-i]), which is
//   bitonic -> log2(L) CE phases re-sort it descending. 3 rounds: 8->4->2->1.
// Then filters its channel (avg ~8 hits), streams its 128 KB x-tile through
// padded LDS, writes selected patches coalesced over d.
// ---------------------------------------------------------------------------
struct GatherSmem {
  float tile[64][65];   // 16,640 B
  int plist[64];        // bytes 16,640..16,896  (beyond key[2048] = 16,384)
  int ilist[64];        // bytes 16,896..17,152
};
union __align__(16) K2Smem {
  u64 key[N_PATCH];     // 16,384 B
  GatherSmem g;         // 17,152 B
};

__global__ __launch_bounds__(256, 4) void merge_gather_kernel(
    const float* __restrict__ x, const u64* __restrict__ chunks,
    float* __restrict__ out) {
  __shared__ K2Smem sm;
  __shared__ int s_m;
  const int bc = blockIdx.x;   // b*32 + c
  const int b  = bc >> 5;
  const int c  = bc & 31;
  const int t  = threadIdx.x;  // 256

#pragma unroll
  for (int l = 0; l < 8; ++l)
    sm.key[l * 256 + t] = chunks[(size_t)b * N_PATCH + l * 256 + t];
  __syncthreads();

  // ---- Round 1: 8 desc lists -> 4 (max-step staged in regs, then merge) --
  {
    u64 r[4];
#pragma unroll
    for (int m = 0; m < 4; ++m) {
      const u64 A = sm.key[(2 * m) * 256 + t];
      const u64 B = sm.key[(2 * m + 1) * 256 + (255 - t)];
      r[m] = A > B ? A : B;
    }
    __syncthreads();
#pragma unroll
    for (int m = 0; m < 4; ++m) sm.key[m * 256 + t] = r[m];
    __syncthreads();
    for (int j = 128; j >= 1; j >>= 1) {   // desc bitonic merge, 4 lists
#pragma unroll
      for (int q = 0; q < 2; ++q) {
        const int pidx = t + q * 256;      // 512 pairs
        const int m  = pidx >> 7;
        const int rk = pidx & 127;
        const int i  = ((rk & ~(j - 1)) << 1) | (rk & (j - 1));
        const int i0 = m * 256 + i;
        const u64 A = sm.key[i0], B = sm.key[i0 + j];
        if (B > A) { sm.key[i0] = B; sm.key[i0 + j] = A; }
      }
      __syncthreads();
    }
  }
  // ---- Round 2: 4 -> 2 ---------------------------------------------------
  {
    u64 r[2];
#pragma unroll
    for (int m = 0; m < 2; ++m) {
      const u64 A = sm.key[(2 * m) * 256 + t];
      const u64 B = sm.key[(2 * m + 1) * 256 + (255 - t)];
      r[m] = A > B ? A : B;
    }
    __syncthreads();
#pragma unroll
    for (int m = 0; m < 2; ++m) sm.key[m * 256 + t] = r[m];
    __syncthreads();
    for (int j = 128; j >= 1; j >>= 1) {   // 256 pairs, 1/thread
      const int m  = t >> 7;
      const int rk = t & 127;
      const int i  = ((rk & ~(j - 1)) << 1) | (rk & (j - 1));
      const int i0 = m * 256 + i;
      const u64 A = sm.key[i0], B = sm.key[i0 + j];
      if (B > A) { sm.key[i0] = B; sm.key[i0 + j] = A; }
      __syncthreads();
    }
  }
  // ---- Round 3: 2 -> 1 (final top-256, desc) -----------------------------
  {
    const u64 A = sm.key[t];
    const u64 B = sm.key[256 + (255 - t)];
    const u64 r = A > B ? A : B;
    __syncthreads();
    sm.key[t] = r;
    __syncthreads();
    for (int j = 128; j >= 1; j >>= 1) {   // 128 pairs
      if (t < 128) {
        const int i  = ((t & ~(j - 1)) << 1) | (t & (j - 1));
        const u64 A2 = sm.key[i], B2 = sm.key[i + j];
        if (B2 > A2) { sm.key[i] = B2; sm.key[i + j] = A2; }
      }
      __syncthreads();
    }
  }

  // ---- Filter my channel (plist/ilist live beyond key[], no overlap) -----
  if (t == 0) s_m = 0;
  __syncthreads();
  {
    const int n = N_PATCH - 1 - (int)(sm.key[t] & 0xFFFFFFFFu);
    if ((n >> 6) == c) {
      const int slot = atomicAdd(&s_m, 1);
      sm.g.plist[slot] = n & 63;
      sm.g.ilist[slot] = t;     // output rank
    }
  }
  __syncthreads();
  const int m = s_m;
  if (m == 0) return;

  // ---- Gather: stream 128 KB tile through padded LDS, coalesced writes ---
  const int p4 = (t & 15) * 4;
  const int r0 = t >> 4;
  const int jr = t >> 6;
  const int dd = t & 63;
  const float* xb = x + (size_t)bc * (D_MODEL * P_DIM);

  float4 pre[4];
#pragma unroll
  for (int q = 0; q < 4; ++q)
    pre[q] = *(const float4*)(xb + (size_t)(r0 + q * 16) * P_DIM + p4);

  for (int d0 = 0; d0 < D_MODEL; d0 += 64) {
    __syncthreads();   // tile region free (key merge done / prev chunk done)
#pragma unroll
    for (int q = 0; q < 4; ++q) {
      const int drow = r0 + q * 16;
      sm.g.tile[drow][p4]     = pre[q].x;
      sm.g.tile[drow][p4 + 1] = pre[q].y;
      sm.g.tile[drow][p4 + 2] = pre[q].z;
      sm.g.tile[drow][p4 + 3] = pre[q].w;
    }
    __syncthreads();
    if (d0 + 64 < D_MODEL) {    // prefetch next chunk; overlaps out-writes
#pragma unroll
      for (int q = 0; q < 4; ++q)
        pre[q] = *(const float4*)(xb + (size_t)(d0 + 64 + r0 + q * 16) * P_DIM + p4);
    }
    for (int j = jr; j < m; j += 4)
      out[(size_t)(b * SELECT_N + sm.g.ilist[j]) * D_MODEL + d0 + dd] =
          sm.g.tile[dd][sm.g.plist[j]];
  }
}

extern "C" void kernel_launch(void* const* d_in, const int* in_sizes, int n_in,
                              void* d_out, int out_size, void* d_ws, size_t ws_size,
                              hipStream_t stream) {
  const float* x = (const float*)d_in[0];
  const float* w = (const float*)d_in[1];
  // d_in[2] (bias) intentionally unused: constant shift doesn't change top-k.

  u64*   chunks = (u64*)d_ws;        // 32 batches x 2048 keys x 8 B = 512 KB
  float* out    = (float*)d_out;

  score_sort_kernel<<<B_DIM * 8, 256, 0, stream>>>(x, w, chunks);
  merge_gather_kernel<<<B_DIM * C_DIM, 256, 0, stream>>>(x, chunks, out);
}

// Round 8
// 226.065 us; speedup vs baseline: 2.5297x; 1.0066x over previous
//
#include <hip/hip_runtime.h>

#define D_MODEL 512
#define P_DIM 64
#define C_DIM 32
#define B_DIM 32
#define N_PATCH 2048   // C_DIM * P_DIM
#define SELECT_N 256

typedef unsigned long long u64;

// ---------------------------------------------------------------------------
// K1: scores + per-chunk sort. One block per (b, chunk); chunk = 4 channels.
// Streams 512 KB (linear-copy pattern), produces 256 scores, bitonic-sorts
// the 256 keys (1 key/thread: stages k<=64 pure shfl, 3 LDS phases for
// j>=64), writes the sorted chunk as u64 keys.
// Key = (monotone_bits<<32) | (2047 - local_n): descending u64 order ==
// score desc, ties -> lower idx (exact jax.lax.top_k semantics; keys unique).
// Bias unused: constant shift doesn't change selection; output is raw x.
// ---------------------------------------------------------------------------
__global__ __launch_bounds__(256) void score_sort_kernel(
    const float* __restrict__ x, const float* __restrict__ w,
    u64* __restrict__ chunks) {
  __shared__ float wl[D_MODEL];
  __shared__ float4 red[16][16];
  __shared__ float cs[256];     // the chunk's 256 scores
  __shared__ u64 skey[256];     // sort scratch

  const int blk   = blockIdx.x;   // b*8 + chunk
  const int b     = blk >> 3;
  const int chunk = blk & 7;
  const int tid   = threadIdx.x;  // 256

  for (int j = tid; j < D_MODEL; j += 256) wl[j] = w[j];
  __syncthreads();

  const int pg    = tid & 15;     // float4 group over p
  const int slice = tid >> 4;     // 0..15

  for (int ch = 0; ch < 4; ++ch) {
    const int bc = b * C_DIM + chunk * 4 + ch;
    const float* base = x + (size_t)bc * (D_MODEL * P_DIM) + pg * 4;
    float4 acc = make_float4(0.f, 0.f, 0.f, 0.f);
#pragma unroll 8
    for (int i = 0; i < 32; ++i) {
      const int d = slice + 16 * i;          // wave-contiguous 1 KB segments
      const float wd = wl[d];
      const float4 v = *(const float4*)(base + (size_t)d * P_DIM);
      acc.x += v.x * wd; acc.y += v.y * wd;
      acc.z += v.z * wd; acc.w += v.w * wd;
    }
    red[slice][pg] = acc;
    __syncthreads();
    if (tid < 16) {
      float4 s = red[0][tid];
#pragma unroll
      for (int k = 1; k < 16; ++k) {
        const float4 t4 = red[k][tid];
        s.x += t4.x; s.y += t4.y; s.z += t4.z; s.w += t4.w;
      }
      cs[ch * 64 + tid * 4 + 0] = s.x;   // p = tid*4+q
      cs[ch * 64 + tid * 4 + 1] = s.y;
      cs[ch * 64 + tid * 4 + 2] = s.z;
      cs[ch * 64 + tid * 4 + 3] = s.w;
    }
    __syncthreads();   // cs visible; red reusable next channel
  }

  // Build key: local element t = ch*64 + p; local_n = chunk*256 + t.
  u64 e;
  {
    unsigned u = __float_as_uint(cs[tid]);
    u ^= (u & 0x80000000u) ? 0xFFFFFFFFu : 0x80000000u;
    e = ((u64)u << 32) | (unsigned)(N_PATCH - 1 - (chunk * 256 + tid));
  }

  auto ce1 = [&](int j, int k) {           // in-wave CE, pair (tid, tid^j)
    const u64 p = __shfl_xor(e, j, 64);
    const bool keepmax = (((tid & j) == 0) == ((tid & k) == 0));
    e = keepmax ? (e > p ? e : p) : (e < p ? e : p);
  };
  auto ldsce = [&](int j, int k) {         // LDS CE, one thread per pair
    if ((tid & j) == 0) {
      const bool desc = ((tid & k) == 0);
      const u64 A = skey[tid], B = skey[tid | j];
      if (desc ? (B > A) : (B < A)) { skey[tid] = B; skey[tid | j] = A; }
    }
  };

#pragma unroll
  for (int kk = 1; kk <= 6; ++kk) {        // stages k = 2..64: pure shfl
    const int k = 1 << kk;
    for (int j = k >> 1; j >= 1; j >>= 1) ce1(j, k);
  }
  // stage k = 128
  skey[tid] = e; __syncthreads();
  ldsce(64, 128); __syncthreads();
  e = skey[tid];
  for (int j = 32; j >= 1; j >>= 1) ce1(j, 128);
  // stage k = 256 (final, all-descending)
  skey[tid] = e; __syncthreads();
  ldsce(128, 256); __syncthreads();
  ldsce(64, 256); __syncthreads();
  e = skey[tid];
  for (int j = 32; j >= 1; j >>= 1) ce1(j, 256);

  chunks[(size_t)b * N_PATCH + chunk * 256 + tid] = e;  // sorted desc
}

// ---------------------------------------------------------------------------
// K2: merge-prune + gather. One block per (b,c). The FIRST gather-tile
// prefetch is issued at kernel entry so its L3 traffic overlaps the merge
// (previously serialized after it). Loads batch b's 8 sorted chunks (16 KB,
// L2/L3-hot) and REDUNDANTLY (per block; device-scope sync costs 200+ us on
// this chip, see R4/R6) reduces them to the sorted top-256 via bitonic
// merge-prune: top-L of two desc L-lists = elementwise max(A[i], B[L-1-i]),
// which is bitonic -> log2(L) CE phases re-sort it. 3 rounds: 8->4->2->1.
// Then filters its channel (avg ~8 hits), streams its 128 KB x-tile through
// padded LDS, writes selected patches coalesced over d.
// ---------------------------------------------------------------------------
struct GatherSmem {
  float tile[64][65];   // 16,640 B
  int plist[64];        // bytes 16,640..16,896  (beyond key[2048] = 16,384)
  int ilist[64];        // bytes 16,896..17,152
};
union __align__(16) K2Smem {
  u64 key[N_PATCH];     // 16,384 B
  GatherSmem g;         // 17,152 B
};

__global__ __launch_bounds__(256, 4) void merge_gather_kernel(
    const float* __restrict__ x, const u64* __restrict__ chunks,
    float* __restrict__ out) {
  __shared__ K2Smem sm;
  __shared__ int s_m;
  const int bc = blockIdx.x;   // b*32 + c
  const int b  = bc >> 5;
  const int c  = bc & 31;
  const int t  = threadIdx.x;  // 256

  const int p4 = (t & 15) * 4;
  const int r0 = t >> 4;
  const int jr = t >> 6;
  const int dd = t & 63;
  const float* xb = x + (size_t)bc * (D_MODEL * P_DIM);

  // Issue chunk-0 tile loads NOW: their latency/BW overlaps the whole merge.
  float4 pre[4];
#pragma unroll
  for (int q = 0; q < 4; ++q)
    pre[q] = *(const float4*)(xb + (size_t)(r0 + q * 16) * P_DIM + p4);

#pragma unroll
  for (int l = 0; l < 8; ++l)
    sm.key[l * 256 + t] = chunks[(size_t)b * N_PATCH + l * 256 + t];
  __syncthreads();

  // ---- Round 1: 8 desc lists -> 4 (max-step staged in regs, then merge) --
  {
    u64 r[4];
#pragma unroll
    for (int m = 0; m < 4; ++m) {
      const u64 A = sm.key[(2 * m) * 256 + t];
      const u64 B = sm.key[(2 * m + 1) * 256 + (255 - t)];
      r[m] = A > B ? A : B;
    }
    __syncthreads();
#pragma unroll
    for (int m = 0; m < 4; ++m) sm.key[m * 256 + t] = r[m];
    __syncthreads();
    for (int j = 128; j >= 1; j >>= 1) {   // desc bitonic merge, 4 lists
#pragma unroll
      for (int q = 0; q < 2; ++q) {
        const int pidx = t + q * 256;      // 512 pairs
        const int m  = pidx >> 7;
        const int rk = pidx & 127;
        const int i  = ((rk & ~(j - 1)) << 1) | (rk & (j - 1));
        const int i0 = m * 256 + i;
        const u64 A = sm.key[i0], B = sm.key[i0 + j];
        if (B > A) { sm.key[i0] = B; sm.key[i0 + j] = A; }
      }
      __syncthreads();
    }
  }
  // ---- Round 2: 4 -> 2 ---------------------------------------------------
  {
    u64 r[2];
#pragma unroll
    for (int m = 0; m < 2; ++m) {
      const u64 A = sm.key[(2 * m) * 256 + t];
      const u64 B = sm.key[(2 * m + 1) * 256 + (255 - t)];
      r[m] = A > B ? A : B;
    }
    __syncthreads();
#pragma unroll
    for (int m = 0; m < 2; ++m) sm.key[m * 256 + t] = r[m];
    __syncthreads();
    for (int j = 128; j >= 1; j >>= 1) {   // 256 pairs, 1/thread
      const int m  = t >> 7;
      const int rk = t & 127;
      const int i  = ((rk & ~(j - 1)) << 1) | (rk & (j - 1));
      const int i0 = m * 256 + i;
      const u64 A = sm.key[i0], B = sm.key[i0 + j];
      if (B > A) { sm.key[i0] = B; sm.key[i0 + j] = A; }
      __syncthreads();
    }
  }
  // ---- Round 3: 2 -> 1 (final top-256, desc) -----------------------------
  {
    const u64 A = sm.key[t];
    const u64 B = sm.key[256 + (255 - t)];
    const u64 r = A > B ? A : B;
    __syncthreads();
    sm.key[t] = r;
    __syncthreads();
    for (int j = 128; j >= 1; j >>= 1) {   // 128 pairs
      if (t < 128) {
        const int i  = ((t & ~(j - 1)) << 1) | (t & (j - 1));
        const u64 A2 = sm.key[i], B2 = sm.key[i + j];
        if (B2 > A2) { sm.key[i] = B2; sm.key[i + j] = A2; }
      }
      __syncthreads();
    }
  }

  // ---- Filter my channel (plist/ilist live beyond key[], no overlap) -----
  if (t == 0) s_m = 0;
  __syncthreads();
  {
    const int n = N_PATCH - 1 - (int)(sm.key[t] & 0xFFFFFFFFu);
    if ((n >> 6) == c) {
      const int slot = atomicAdd(&s_m, 1);
      sm.g.plist[slot] = n & 63;
      sm.g.ilist[slot] = t;     // output rank
    }
  }
  __syncthreads();
  const int m = s_m;
  if (m == 0) return;

  // ---- Gather: stream 128 KB tile through padded LDS, coalesced writes ---
  for (int d0 = 0; d0 < D_MODEL; d0 += 64) {
    __syncthreads();   // tile region free (key merge done / prev chunk done)
#pragma unroll
    for (int q = 0; q < 4; ++q) {
      const int drow = r0 + q * 16;
      sm.g.tile[drow][p4]     = pre[q].x;
      sm.g.tile[drow][p4 + 1] = pre[q].y;
      sm.g.tile[drow][p4 + 2] = pre[q].z;
      sm.g.tile[drow][p4 + 3] = pre[q].w;
    }
    __syncthreads();
    if (d0 + 64 < D_MODEL) {    // prefetch next chunk; overlaps out-writes
#pragma unroll
      for (int q = 0; q < 4; ++q)
        pre[q] = *(const float4*)(xb + (size_t)(d0 + 64 + r0 + q * 16) * P_DIM + p4);
    }
    for (int j = jr; j < m; j += 4)
      out[(size_t)(b * SELECT_N + sm.g.ilist[j]) * D_MODEL + d0 + dd] =
          sm.g.tile[dd][sm.g.plist[j]];
  }
}

extern "C" void kernel_launch(void* const* d_in, const int* in_sizes, int n_in,
                              void* d_out, int out_size, void* d_ws, size_t ws_size,
                              hipStream_t stream) {
  const float* x = (const float*)d_in[0];
  const float* w = (const float*)d_in[1];
  // d_in[2] (bias) intentionally unused: constant shift doesn't change top-k.

  u64*   chunks = (u64*)d_ws;        // 32 batches x 2048 keys x 8 B = 512 KB
  float* out    = (float*)d_out;

  score_sort_kernel<<<B_DIM * 8, 256, 0, stream>>>(x, w, chunks);
  merge_gather_kernel<<<B_DIM * C_DIM, 256, 0, stream>>>(x, chunks, out);
}